// Round 12
// baseline (386.148 us; speedup 1.0000x reference)
//
#include <hip/hip_runtime.h>
#include <hip/hip_fp16.h>

#define NN 50000
#define NE 1600000
#define DD 128
#define NH 9
#define NC 8
#define HCH 72
#define NEG 0.2f
#define NBUCK 196      // ceil(50000/256), 256 dst nodes per bucket
#define NSEG 16        // src segments of 4096 nodes (only 0..12 non-empty)
#define SPAD 17        // padded seg stride in k_scat2 LDS (bank-conflict fix)
#define EPB 16         // edges per thread in bin part
#define BCH (256*EPB)  // 4096 edges per bin block
#define BSTRIDE 10240  // fixed per-bucket capacity (mean 8192, sigma 90 -> +22 sigma)
#define BCSTRIDE 16    // bcursor padded to 64B/bucket
#define GEMMB2 ((NN + 63) / 64)          // 782 mfma-gemm blocks (64 nodes each)
#define BINB ((NE + BCH - 1) / BCH)      // 391 bin blocks
#define AGGB ((NN * NH + 255) / 256)     // 1758 agg blocks per graph
#define CLP 88         // padded col-stride of C LDS tile (fp16)

typedef _Float16 f16x8 __attribute__((ext_vector_type(8)));
typedef float f32x4 __attribute__((ext_vector_type(4)));

__device__ __forceinline__ unsigned short f2h(float f) {
  return __half_as_ushort(__float2half_rn(f));
}
__device__ __forceinline__ float h2f(unsigned short u) {
  return __half2float(__ushort_as_half(u));
}
__device__ __forceinline__ float hlo(unsigned u) {
  return __half2float(__ushort_as_half((unsigned short)(u & 0xFFFFu)));
}
__device__ __forceinline__ float hhi(unsigned u) {
  return __half2float(__ushort_as_half((unsigned short)(u >> 16)));
}

struct GP {
  const float* x; const int* ei; const float* W;
  const float* as; const float* ad; const float* b;
  uint4* h2;                // [NN*9] uint4: 8 fp16 channels per (node,head)
  float* a_d; float* out;
  _Float16* wf;             // [4*5*64*8] fragment-ordered fp16 W (20KB, k_wpack)
  int* offs2;               // [NBUCK*256*16] per-(node,seg) absolute csr offsets
  int* bcursor;             // [NBUCK*BCSTRIDE] bucket fill counts (64B-padded, atomic)
  unsigned int* pairs;      // [NBUCK*BSTRIDE] strided bucket runs
  int* csr;                 // [NBUCK*BSTRIDE]
};
struct GT { GP g[3]; };

// R12: a_s is RECOMPUTED in k_agg from the h2 channels already in registers
// (dot with att_src) — removes the third gather load per edge (as2 array is
// gone). Same fp32 dot k_fat used, minus the fp16 round-trip.
__device__ __forceinline__ void accum2(uint4 v, const float4 As0, const float4 As1,
                                       float ad_n, float& denom,
                                       float4& acc0, float4& acc1) {
  const float h0 = hlo(v.x), h1 = hhi(v.x), h2v = hlo(v.y), h3 = hhi(v.y);
  const float h4 = hlo(v.z), h5 = hhi(v.z), h6 = hlo(v.w), h7 = hhi(v.w);
  const float s = h0 * As0.x + h1 * As0.y + h2v * As0.z + h3 * As0.w
                + h4 * As1.x + h5 * As1.y + h6 * As1.z + h7 * As1.w;
  float tt = s + ad_n;
  tt = (tt > 0.f) ? tt : NEG * tt;
  const float w = __expf(tt);
  denom += w;
  acc0.x = fmaf(w, h0, acc0.x); acc0.y = fmaf(w, h1, acc0.y);
  acc0.z = fmaf(w, h2v, acc0.z); acc0.w = fmaf(w, h3, acc0.w);
  acc1.x = fmaf(w, h4, acc1.x); acc1.y = fmaf(w, h5, acc1.y);
  acc1.z = fmaf(w, h6, acc1.z); acc1.w = fmaf(w, h7, acc1.w);
}

// Pre-pack W into MFMA B-fragment order, fp16, ONCE per graph. Also zeroes
// bcursor (folded from the former hipMemsetAsync dispatch).
// wf[((ks*5+ct)*64+lane)*8+j] = fp16(W[ks*32+(lane>>4)*8+j][ct*16+(lane&15)])
__global__ __launch_bounds__(256) void k_wpack(GT t) {
  const GP G = t.g[blockIdx.z];
  const int tid = threadIdx.x;
  for (int i = tid; i < NBUCK * BCSTRIDE; i += 256) G.bcursor[i] = 0;
  for (int idx = tid; idx < 4 * 5 * 64 * 8; idx += 256) {
    const int j = idx & 7;
    const int lane = (idx >> 3) & 63;
    const int ctks = idx >> 9;           // 0..19
    const int ct = ctks % 5;
    const int ks = ctks / 5;
    const int k = ks * 32 + ((lane >> 4) << 3) + j;
    const int col = ct * 16 + (lane & 15);
    const float v = (col < HCH) ? G.W[k * HCH + col] : 0.f;
    G.wf[idx] = (_Float16)v;
  }
}

// Fused bin + gemm (independent stages overlap on the CUs).
// x < BINB: bin edges into fixed-stride bucket runs (LDS sort, coalesced out).
// x >= BINB: h = x@W via MFMA fp16 with pre-packed wf (L2-broadcast B-frags).
__global__ __launch_bounds__(256) void k_fat(GT t) {
  const GP G = t.g[blockIdx.z];
  __shared__ __align__(16) char smem[23072];   // union: bin 23.0KB / gemm 11.3KB
  const int tid = threadIdx.x;

  if (blockIdx.x < BINB) {
    // ---- bin part ----
    unsigned* stage = (unsigned*)smem;                       // 16384 B
    unsigned char* bkt = (unsigned char*)(smem + 16384);     // 4096 B
    int* hist   = (int*)(smem + 20480);                      // 784 B
    int* gdelta = (int*)(smem + 21264);                      // 784 B
    int* ssum   = (int*)(smem + 22048);                      // 1024 B
    const int e0 = blockIdx.x * BCH;

    for (int i = tid; i < NBUCK; i += 256) hist[i] = 0;
    __syncthreads();
    int dsts[EPB], srcs[EPB];
    #pragma unroll
    for (int k = 0; k < EPB; ++k) {
      const int e = e0 + k * 256 + tid;
      if (e < NE) {
        dsts[k] = G.ei[NE + e];
        srcs[k] = G.ei[e];
        atomicAdd(&hist[dsts[k] >> 8], 1);
      } else dsts[k] = -1;
    }
    __syncthreads();
    // exclusive scan over the 196 bucket counts (Hillis-Steele, 256 threads)
    const int cnt_t = (tid < NBUCK) ? hist[tid] : 0;
    ssum[tid] = cnt_t;
    __syncthreads();
    int run = cnt_t;
    for (int off = 1; off < 256; off <<= 1) {
      int u = (tid >= off) ? ssum[tid - off] : 0;
      __syncthreads();
      run += u;
      ssum[tid] = run;
      __syncthreads();
    }
    const int excl = run - cnt_t;
    if (tid < NBUCK) {
      const int gbase = cnt_t ? atomicAdd(&G.bcursor[tid * BCSTRIDE], cnt_t) : 0;
      gdelta[tid] = tid * BSTRIDE + gbase - excl;
      hist[tid] = excl;                  // counts dead; reuse as scatter cursors
    }
    __syncthreads();
    #pragma unroll
    for (int k = 0; k < EPB; ++k) {
      if (dsts[k] >= 0) {
        const int b = dsts[k] >> 8;
        const int pos = atomicAdd(&hist[b], 1);
        stage[pos] = (unsigned)srcs[k] | ((unsigned)(dsts[k] & 255) << 16);
        bkt[pos] = (unsigned char)b;
      }
    }
    __syncthreads();
    const int total = (e0 + BCH <= NE) ? BCH : (NE - e0);
    for (int i = tid; i < total; i += 256) {
      const int b = bkt[i];
      const int addr = gdelta[b] + i;    // = b*BSTRIDE + gbase + (i - lstart[b])
      if (addr - b * BSTRIDE < BSTRIDE)  // overflow guard (effectively never)
        G.pairs[addr] = stage[i];
    }
    return;
  }

  // ---- gemm part ----
  _Float16* Cl = (_Float16*)smem;                      // [64][CLP] 11264 B
  const int wv = tid >> 6;       // wave 0..3 -> rows wv*16..wv*16+15
  const int ln = tid & 63;
  const int rl = ln & 15;        // A row within 16 / B col within 16
  const int kg = ln >> 4;        // k-group 0..3 (8 consecutive k each)
  const int n0 = (blockIdx.x - BINB) << 6;
  int arow = n0 + wv * 16 + rl;
  if (arow >= NN) arow = NN - 1;            // clamp: loads stay in-bounds, stores guarded
  const float4* xr = (const float4*)(G.x + (size_t)arow * DD) + (kg << 1);
  const f16x8* wfp = (const f16x8*)G.wf;

  f32x4 acc[5];
  #pragma unroll
  for (int ct = 0; ct < 5; ++ct) acc[ct] = (f32x4){0.f, 0.f, 0.f, 0.f};

  #pragma unroll
  for (int ks = 0; ks < 4; ++ks) {
    const float4 xa = xr[ks * 8];           // floats kg*8 + ks*32 .. +3
    const float4 xb = xr[ks * 8 + 1];       // .. +7
    float xs[8] = {xa.x, xa.y, xa.z, xa.w, xb.x, xb.y, xb.z, xb.w};
    f16x8 ahi, alo;
    #pragma unroll
    for (int j = 0; j < 8; ++j) {
      const _Float16 h = (_Float16)xs[j];
      ahi[j] = h;
      alo[j] = (_Float16)(xs[j] - (float)h);   // residual: near-fp32 A path
    }
    #pragma unroll
    for (int ct = 0; ct < 5; ++ct) {
      const f16x8 bf = wfp[(ks * 5 + ct) * 64 + ln];
      acc[ct] = __builtin_amdgcn_mfma_f32_16x16x32_f16(ahi, bf, acc[ct], 0, 0, 0);
      acc[ct] = __builtin_amdgcn_mfma_f32_16x16x32_f16(alo, bf, acc[ct], 0, 0, 0);
    }
  }

  // C/D layout (HW-verified): col = lane&15, row = (lane>>4)*4 + reg
  #pragma unroll
  for (int ct = 0; ct < 5; ++ct) {
    #pragma unroll
    for (int j = 0; j < 4; ++j)
      Cl[(wv * 16 + kg * 4 + j) * CLP + ct * 16 + rl] = (_Float16)acc[ct][j];
  }
  __syncthreads();

  // epilogue: per (node,head) pair, h2 is the packed uint4 straight from LDS.
  // (a_s no longer stored — k_agg recomputes it from h2; only a_d kept.)
  for (int p = tid; p < 64 * NH; p += 256) {
    const int node = p / NH;
    const int hd = p - node * NH;
    const int n = n0 + node;
    if (n >= NN) continue;
    const uint4 hv = *(const uint4*)&Cl[node * CLP + hd * NC];
    const float h0 = hlo(hv.x), h1 = hhi(hv.x), h2v = hlo(hv.y), h3 = hhi(hv.y);
    const float h4 = hlo(hv.z), h5 = hhi(hv.z), h6 = hlo(hv.w), h7 = hhi(hv.w);
    const float4 Ad0 = *(const float4*)(G.ad + hd * NC);
    const float4 Ad1 = *(const float4*)(G.ad + hd * NC + 4);
    const float sdst = h0 * Ad0.x + h1 * Ad0.y + h2v * Ad0.z + h3 * Ad0.w
                     + h4 * Ad1.x + h5 * Ad1.y + h6 * Ad1.z + h7 * Ad1.w;
    G.h2[(size_t)n * NH + hd] = hv;
    G.a_d[n * NH + hd] = sdst;
  }
}

// One block per bucket. LDS counting sort with key (dst_local,seg); sorted
// src values staged in LDS ushort, then coalesced copy-out to csr.
__global__ __launch_bounds__(256) void k_scat2(GT t) {
  const GP G = t.g[blockIdx.z];
  const int b = blockIdx.x;
  const int d0 = b << 8;
  __shared__ int cnt[256 * SPAD];            // 17.4 KB (counts, then LOCAL cursors)
  __shared__ int ssum[256];
  __shared__ unsigned short stage[BSTRIDE];  // 20.5 KB sorted src values
  const int tid = threadIdx.x;
  const int estart = b * BSTRIDE;
  const int count0 = G.bcursor[b * BCSTRIDE];
  const int count = (count0 < BSTRIDE) ? count0 : BSTRIDE;   // clamp (never in practice)
  const int eend = estart + count;
  for (int i = tid; i < 256 * SPAD; i += 256) cnt[i] = 0;
  __syncthreads();
  for (int e = estart + tid; e < eend; e += 256) {
    unsigned p = G.pairs[e];
    int key = (int)((p >> 16) * SPAD + ((p & 0xFFFFu) >> 12));
    atomicAdd(&cnt[key], 1);
  }
  __syncthreads();
  int local[NSEG];
  int sum = 0;
  #pragma unroll
  for (int i = 0; i < NSEG; ++i) { local[i] = sum; sum += cnt[tid * SPAD + i]; }
  ssum[tid] = sum;
  __syncthreads();
  int run = sum;
  for (int off = 1; off < 256; off <<= 1) {
    int u = (tid >= off) ? ssum[tid - off] : 0;
    __syncthreads();
    run += u;
    ssum[tid] = run;
    __syncthreads();
  }
  const int texcl = run - sum;
  int* o2 = G.offs2 + ((size_t)d0 << 4);
  #pragma unroll
  for (int i = 0; i < NSEG; ++i) {
    const int v = texcl + local[i];         // bucket-LOCAL offset
    cnt[tid * SPAD + i] = v;                // counts dead; reuse as local cursors
    o2[tid * NSEG + i] = estart + v;        // offs2 stays ABSOLUTE
  }
  __syncthreads();
  for (int e = estart + tid; e < eend; e += 256) {
    unsigned p = G.pairs[e];
    int key = (int)((p >> 16) * SPAD + ((p & 0xFFFFu) >> 12));
    int lpos = atomicAdd(&cnt[key], 1);
    if (lpos < BSTRIDE)
      stage[lpos] = (unsigned short)(p & 0xFFFFu);
  }
  __syncthreads();
  // coalesced copy-out: dense sequential 4B stores -> full-line writebacks
  for (int i = tid; i < count; i += 256)
    G.csr[estart + i] = (int)stage[i];
}

// gather aggregation: thread (dst,head), barrier every 4 src-segments,
// 4-edge batched loads, graph-major fused. R12: 2 loads/edge (csr + h2);
// a_s recomputed in-register from h2 channels (accum2) — cuts the
// address-divergent gather instruction/line count ~30%.
__global__ __launch_bounds__(256) void k_agg(GT t) {
  const int g = blockIdx.x / AGGB;
  const GP G = t.g[g];
  const int gid = (blockIdx.x - g * AGGB) * 256 + threadIdx.x;
  const bool active = (gid < NN * NH);
  int n = 0, head = 0;
  if (active) { n = gid / NH; head = gid - n * NH; }
  float denom = 0.f;
  float4 acc0 = make_float4(0.f, 0.f, 0.f, 0.f);
  float4 acc1 = make_float4(0.f, 0.f, 0.f, 0.f);
  float ad_n = 0.f;
  float4 As0 = make_float4(0.f, 0.f, 0.f, 0.f);
  float4 As1 = make_float4(0.f, 0.f, 0.f, 0.f);
  int gb[5] = {0, 0, 0, 0, 0};
  if (active) {
    ad_n = G.a_d[n * NH + head];
    As0 = *(const float4*)(G.as + head * NC);
    As1 = *(const float4*)(G.as + head * NC + 4);
    const int* o2 = G.offs2 + ((size_t)n << 4);
    gb[0] = o2[0]; gb[1] = o2[4]; gb[2] = o2[8]; gb[3] = o2[12]; gb[4] = o2[13];
    const uint4 hs = G.h2[(size_t)n * NH + head];
    accum2(hs, As0, As1, ad_n, denom, acc0, acc1);   // self-loop
  }
  #pragma unroll
  for (int sgrp = 0; sgrp < 4; ++sgrp) {
    int e = gb[sgrp];
    const int en = gb[sgrp + 1];
    for (; e + 4 <= en; e += 4) {
      const int s0 = G.csr[e];
      const int s1 = G.csr[e + 1];
      const int s2 = G.csr[e + 2];
      const int s3 = G.csr[e + 3];
      const uint4 v0 = G.h2[(size_t)s0 * NH + head];
      const uint4 v1 = G.h2[(size_t)s1 * NH + head];
      const uint4 v2 = G.h2[(size_t)s2 * NH + head];
      const uint4 v3 = G.h2[(size_t)s3 * NH + head];
      accum2(v0, As0, As1, ad_n, denom, acc0, acc1);
      accum2(v1, As0, As1, ad_n, denom, acc0, acc1);
      accum2(v2, As0, As1, ad_n, denom, acc0, acc1);
      accum2(v3, As0, As1, ad_n, denom, acc0, acc1);
    }
    for (; e < en; ++e) {
      const int src = G.csr[e];
      const uint4 hv = G.h2[(size_t)src * NH + head];
      accum2(hv, As0, As1, ad_n, denom, acc0, acc1);
    }
    __syncthreads();
  }
  if (!active) return;
  float inv = 1.f / (denom + 1e-16f);
  const float* bp = G.b + head * NC;
  float4 o0, o1;
  o0.x = acc0.x * inv + bp[0]; o0.y = acc0.y * inv + bp[1];
  o0.z = acc0.z * inv + bp[2]; o0.w = acc0.w * inv + bp[3];
  o1.x = acc1.x * inv + bp[4]; o1.y = acc1.y * inv + bp[5];
  o1.z = acc1.z * inv + bp[6]; o1.w = acc1.w * inv + bp[7];
  float4* op = (float4*)(G.out + (size_t)n * HCH + head * NC);
  op[0] = o0; op[1] = o1;
}

// relu(concat) @ fnn_W + fnn_b -> softmax(2). One wave per node.
__global__ __launch_bounds__(256) void k_fnn(const float* __restrict__ o1,
                                             const float* __restrict__ o2,
                                             const float* __restrict__ o3,
                                             const float* __restrict__ fw,
                                             const float* __restrict__ fb,
                                             float* __restrict__ out) {
  const int tid = blockIdx.x * 256 + threadIdx.x;
  const int n = tid >> 6;
  const int lane = tid & 63;
  if (n >= NN) return;
  float acc0 = 0.f, acc1 = 0.f;
  for (int j = lane; j < 3 * HCH; j += 64) {
    const int g = j / HCH;
    const int c = j - g * HCH;
    const float* og = (g == 0) ? o1 : (g == 1) ? o2 : o3;
    float v = og[(size_t)n * HCH + c];
    v = v > 0.f ? v : 0.f;
    acc0 = fmaf(v, fw[2 * j], acc0);
    acc1 = fmaf(v, fw[2 * j + 1], acc1);
  }
  #pragma unroll
  for (int off = 32; off > 0; off >>= 1) {
    acc0 += __shfl_down(acc0, off, 64);
    acc1 += __shfl_down(acc1, off, 64);
  }
  if (lane == 0) {
    float l0 = acc0 + fb[0], l1 = acc1 + fb[1];
    float m = fmaxf(l0, l1);
    float e0 = __expf(l0 - m), e1 = __expf(l1 - m);
    float inv = 1.f / (e0 + e1);
    out[(size_t)n * 2] = e0 * inv;
    out[(size_t)n * 2 + 1] = e1 * inv;
  }
}

extern "C" void kernel_launch(void* const* d_in, const int* in_sizes, int n_in,
                              void* d_out, int out_size, void* d_ws, size_t ws_size,
                              hipStream_t stream) {
  (void)in_sizes; (void)n_in; (void)out_size; (void)ws_size;
  GT t;
  char* w = (char*)d_ws;
  size_t off = 0;
  auto carve = [&](size_t bytes) -> void* {
    void* p = w + off;
    off = (off + bytes + 255) & ~(size_t)255;
    return p;
  };
  int* bc_all = (int*)carve(3 * NBUCK * BCSTRIDE * 4);   // 3 graphs' padded bcursor
  for (int g = 0; g < 3; ++g) {
    GP& G = t.g[g];
    G.x  = (const float*)d_in[6 * g + 0];
    G.ei = (const int*)d_in[6 * g + 1];     // harness stores int64 inputs as int32
    G.W  = (const float*)d_in[6 * g + 2];
    G.as = (const float*)d_in[6 * g + 3];
    G.ad = (const float*)d_in[6 * g + 4];
    G.b  = (const float*)d_in[6 * g + 5];
    G.bcursor = bc_all + g * NBUCK * BCSTRIDE;
    G.h2   = (uint4*)carve((size_t)NN * NH * 16);
    G.a_d  = (float*)carve((size_t)NN * NH * 4);
    G.out  = (float*)carve((size_t)NN * HCH * 4);
    G.wf   = (_Float16*)carve((size_t)4 * 5 * 64 * 8 * 2);
    G.offs2 = (int*)carve((size_t)NBUCK * 256 * NSEG * 4);
    G.pairs = (unsigned int*)carve((size_t)NBUCK * BSTRIDE * 4);
    G.csr   = (int*)carve((size_t)NBUCK * BSTRIDE * 4);
  }
  const float* fw = (const float*)d_in[18];
  const float* fb = (const float*)d_in[19];
  float* outp = (float*)d_out;

  dim3 b256(256, 1, 1);
  k_wpack <<<dim3(1, 1, 3), b256, 0, stream>>>(t);
  k_fat   <<<dim3(BINB + GEMMB2, 1, 3), b256, 0, stream>>>(t);
  k_scat2 <<<dim3(NBUCK, 1, 3), b256, 0, stream>>>(t);
  k_agg   <<<dim3(AGGB * 3, 1, 1), b256, 0, stream>>>(t);
  k_fnn   <<<(NN * 64 + 255) / 256, b256, 0, stream>>>(t.g[0].out, t.g[1].out, t.g[2].out, fw, fb, outp);
}

// Round 13
// 364.988 us; speedup vs baseline: 1.0580x; 1.0580x over previous
//
#include <hip/hip_runtime.h>
#include <hip/hip_fp16.h>

#define NN 50000
#define NE 1600000
#define DD 128
#define NH 9
#define NC 8
#define HCH 72
#define NEG 0.2f
#define NBUCK 196      // ceil(50000/256), 256 dst nodes per bucket
#define NSEG 16        // src segments of 4096 nodes (only 0..12 non-empty)
#define SPAD 17        // padded seg stride in k_scat2 LDS (bank-conflict fix)
#define EPB 16         // edges per thread in bin part
#define BCH (256*EPB)  // 4096 edges per bin block
#define BSTRIDE 10240  // fixed per-bucket capacity (mean 8192, sigma 90 -> +22 sigma)
#define BCSTRIDE 16    // bcursor padded to 64B/bucket
#define GEMMB2 ((NN + 63) / 64)          // 782 mfma-gemm blocks (64 nodes each)
#define BINB ((NE + BCH - 1) / BCH)      // 391 bin blocks
#define AGGB ((NN * NH + 255) / 256)     // 1758 agg blocks per graph
#define CLP 88         // padded col-stride of C LDS tile (fp16)
#define MAXND 30       // max nodes per agg block (ceil(256/9)+1)
#define LCAP 2816      // LDS csr capacity per agg block (mean 928, +62 sigma)

typedef _Float16 f16x8 __attribute__((ext_vector_type(8)));
typedef float f32x4 __attribute__((ext_vector_type(4)));

__device__ __forceinline__ unsigned short f2h(float f) {
  return __half_as_ushort(__float2half_rn(f));
}
__device__ __forceinline__ float h2f(unsigned short u) {
  return __half2float(__ushort_as_half(u));
}
__device__ __forceinline__ float hlo(unsigned u) {
  return __half2float(__ushort_as_half((unsigned short)(u & 0xFFFFu)));
}
__device__ __forceinline__ float hhi(unsigned u) {
  return __half2float(__ushort_as_half((unsigned short)(u >> 16)));
}

struct GP {
  const float* x; const int* ei; const float* W;
  const float* as; const float* ad; const float* b;
  uint4* h2;                // [NN*9] uint4: 8 fp16 channels per (node,head)
  float* a_d; float* out;
  _Float16* wf;             // [4*5*64*8] fragment-ordered fp16 W (20KB, k_wpack)
  int* offs2;               // [NBUCK*256*16] per-(node,seg) absolute csr offsets
  int* bcursor;             // [NBUCK*BCSTRIDE] bucket fill counts (64B-padded, atomic)
  unsigned int* pairs;      // [NBUCK*BSTRIDE] strided bucket runs
  int* csr;                 // [NBUCK*BSTRIDE]
};
struct GT { GP g[3]; };

// a_s recomputed from h2 channels already in registers (R12-proven: -25% FETCH).
__device__ __forceinline__ void accum2(uint4 v, const float4 As0, const float4 As1,
                                       float ad_n, float& denom,
                                       float4& acc0, float4& acc1) {
  const float h0 = hlo(v.x), h1 = hhi(v.x), h2v = hlo(v.y), h3 = hhi(v.y);
  const float h4 = hlo(v.z), h5 = hhi(v.z), h6 = hlo(v.w), h7 = hhi(v.w);
  const float s = h0 * As0.x + h1 * As0.y + h2v * As0.z + h3 * As0.w
                + h4 * As1.x + h5 * As1.y + h6 * As1.z + h7 * As1.w;
  float tt = s + ad_n;
  tt = (tt > 0.f) ? tt : NEG * tt;
  const float w = __expf(tt);
  denom += w;
  acc0.x = fmaf(w, h0, acc0.x); acc0.y = fmaf(w, h1, acc0.y);
  acc0.z = fmaf(w, h2v, acc0.z); acc0.w = fmaf(w, h3, acc0.w);
  acc1.x = fmaf(w, h4, acc1.x); acc1.y = fmaf(w, h5, acc1.y);
  acc1.z = fmaf(w, h6, acc1.z); acc1.w = fmaf(w, h7, acc1.w);
}

// Pre-pack W into MFMA B-fragment order, fp16, ONCE per graph. Also zeroes
// bcursor (folded from the former hipMemsetAsync dispatch).
__global__ __launch_bounds__(256) void k_wpack(GT t) {
  const GP G = t.g[blockIdx.z];
  const int tid = threadIdx.x;
  for (int i = tid; i < NBUCK * BCSTRIDE; i += 256) G.bcursor[i] = 0;
  for (int idx = tid; idx < 4 * 5 * 64 * 8; idx += 256) {
    const int j = idx & 7;
    const int lane = (idx >> 3) & 63;
    const int ctks = idx >> 9;           // 0..19
    const int ct = ctks % 5;
    const int ks = ctks / 5;
    const int k = ks * 32 + ((lane >> 4) << 3) + j;
    const int col = ct * 16 + (lane & 15);
    const float v = (col < HCH) ? G.W[k * HCH + col] : 0.f;
    G.wf[idx] = (_Float16)v;
  }
}

// Fused bin + gemm (independent stages overlap on the CUs).
__global__ __launch_bounds__(256) void k_fat(GT t) {
  const GP G = t.g[blockIdx.z];
  __shared__ __align__(16) char smem[23072];   // union: bin 23.0KB / gemm 11.3KB
  const int tid = threadIdx.x;

  if (blockIdx.x < BINB) {
    // ---- bin part ----
    unsigned* stage = (unsigned*)smem;                       // 16384 B
    unsigned char* bkt = (unsigned char*)(smem + 16384);     // 4096 B
    int* hist   = (int*)(smem + 20480);                      // 784 B
    int* gdelta = (int*)(smem + 21264);                      // 784 B
    int* ssum   = (int*)(smem + 22048);                      // 1024 B
    const int e0 = blockIdx.x * BCH;

    for (int i = tid; i < NBUCK; i += 256) hist[i] = 0;
    __syncthreads();
    int dsts[EPB], srcs[EPB];
    #pragma unroll
    for (int k = 0; k < EPB; ++k) {
      const int e = e0 + k * 256 + tid;
      if (e < NE) {
        dsts[k] = G.ei[NE + e];
        srcs[k] = G.ei[e];
        atomicAdd(&hist[dsts[k] >> 8], 1);
      } else dsts[k] = -1;
    }
    __syncthreads();
    const int cnt_t = (tid < NBUCK) ? hist[tid] : 0;
    ssum[tid] = cnt_t;
    __syncthreads();
    int run = cnt_t;
    for (int off = 1; off < 256; off <<= 1) {
      int u = (tid >= off) ? ssum[tid - off] : 0;
      __syncthreads();
      run += u;
      ssum[tid] = run;
      __syncthreads();
    }
    const int excl = run - cnt_t;
    if (tid < NBUCK) {
      const int gbase = cnt_t ? atomicAdd(&G.bcursor[tid * BCSTRIDE], cnt_t) : 0;
      gdelta[tid] = tid * BSTRIDE + gbase - excl;
      hist[tid] = excl;                  // counts dead; reuse as scatter cursors
    }
    __syncthreads();
    #pragma unroll
    for (int k = 0; k < EPB; ++k) {
      if (dsts[k] >= 0) {
        const int b = dsts[k] >> 8;
        const int pos = atomicAdd(&hist[b], 1);
        stage[pos] = (unsigned)srcs[k] | ((unsigned)(dsts[k] & 255) << 16);
        bkt[pos] = (unsigned char)b;
      }
    }
    __syncthreads();
    const int total = (e0 + BCH <= NE) ? BCH : (NE - e0);
    for (int i = tid; i < total; i += 256) {
      const int b = bkt[i];
      const int addr = gdelta[b] + i;
      if (addr - b * BSTRIDE < BSTRIDE)
        G.pairs[addr] = stage[i];
    }
    return;
  }

  // ---- gemm part ----
  _Float16* Cl = (_Float16*)smem;                      // [64][CLP] 11264 B
  const int wv = tid >> 6;
  const int ln = tid & 63;
  const int rl = ln & 15;
  const int kg = ln >> 4;
  const int n0 = (blockIdx.x - BINB) << 6;
  int arow = n0 + wv * 16 + rl;
  if (arow >= NN) arow = NN - 1;
  const float4* xr = (const float4*)(G.x + (size_t)arow * DD) + (kg << 1);
  const f16x8* wfp = (const f16x8*)G.wf;

  f32x4 acc[5];
  #pragma unroll
  for (int ct = 0; ct < 5; ++ct) acc[ct] = (f32x4){0.f, 0.f, 0.f, 0.f};

  #pragma unroll
  for (int ks = 0; ks < 4; ++ks) {
    const float4 xa = xr[ks * 8];
    const float4 xb = xr[ks * 8 + 1];
    float xs[8] = {xa.x, xa.y, xa.z, xa.w, xb.x, xb.y, xb.z, xb.w};
    f16x8 ahi, alo;
    #pragma unroll
    for (int j = 0; j < 8; ++j) {
      const _Float16 h = (_Float16)xs[j];
      ahi[j] = h;
      alo[j] = (_Float16)(xs[j] - (float)h);
    }
    #pragma unroll
    for (int ct = 0; ct < 5; ++ct) {
      const f16x8 bf = wfp[(ks * 5 + ct) * 64 + ln];
      acc[ct] = __builtin_amdgcn_mfma_f32_16x16x32_f16(ahi, bf, acc[ct], 0, 0, 0);
      acc[ct] = __builtin_amdgcn_mfma_f32_16x16x32_f16(alo, bf, acc[ct], 0, 0, 0);
    }
  }

  #pragma unroll
  for (int ct = 0; ct < 5; ++ct) {
    #pragma unroll
    for (int j = 0; j < 4; ++j)
      Cl[(wv * 16 + kg * 4 + j) * CLP + ct * 16 + rl] = (_Float16)acc[ct][j];
  }
  __syncthreads();

  for (int p = tid; p < 64 * NH; p += 256) {
    const int node = p / NH;
    const int hd = p - node * NH;
    const int n = n0 + node;
    if (n >= NN) continue;
    const uint4 hv = *(const uint4*)&Cl[node * CLP + hd * NC];
    const float h0 = hlo(hv.x), h1 = hhi(hv.x), h2v = hlo(hv.y), h3 = hhi(hv.y);
    const float h4 = hlo(hv.z), h5 = hhi(hv.z), h6 = hlo(hv.w), h7 = hhi(hv.w);
    const float4 Ad0 = *(const float4*)(G.ad + hd * NC);
    const float4 Ad1 = *(const float4*)(G.ad + hd * NC + 4);
    const float sdst = h0 * Ad0.x + h1 * Ad0.y + h2v * Ad0.z + h3 * Ad0.w
                     + h4 * Ad1.x + h5 * Ad1.y + h6 * Ad1.z + h7 * Ad1.w;
    G.h2[(size_t)n * NH + hd] = hv;
    G.a_d[n * NH + hd] = sdst;
  }
}

// One block per bucket. LDS counting sort with key (dst_local,seg); sorted
// src values staged in LDS ushort, then coalesced copy-out to csr.
__global__ __launch_bounds__(256) void k_scat2(GT t) {
  const GP G = t.g[blockIdx.z];
  const int b = blockIdx.x;
  const int d0 = b << 8;
  __shared__ int cnt[256 * SPAD];
  __shared__ int ssum[256];
  __shared__ unsigned short stage[BSTRIDE];
  const int tid = threadIdx.x;
  const int estart = b * BSTRIDE;
  const int count0 = G.bcursor[b * BCSTRIDE];
  const int count = (count0 < BSTRIDE) ? count0 : BSTRIDE;
  const int eend = estart + count;
  for (int i = tid; i < 256 * SPAD; i += 256) cnt[i] = 0;
  __syncthreads();
  for (int e = estart + tid; e < eend; e += 256) {
    unsigned p = G.pairs[e];
    int key = (int)((p >> 16) * SPAD + ((p & 0xFFFFu) >> 12));
    atomicAdd(&cnt[key], 1);
  }
  __syncthreads();
  int local[NSEG];
  int sum = 0;
  #pragma unroll
  for (int i = 0; i < NSEG; ++i) { local[i] = sum; sum += cnt[tid * SPAD + i]; }
  ssum[tid] = sum;
  __syncthreads();
  int run = sum;
  for (int off = 1; off < 256; off <<= 1) {
    int u = (tid >= off) ? ssum[tid - off] : 0;
    __syncthreads();
    run += u;
    ssum[tid] = run;
    __syncthreads();
  }
  const int texcl = run - sum;
  int* o2 = G.offs2 + ((size_t)d0 << 4);
  #pragma unroll
  for (int i = 0; i < NSEG; ++i) {
    const int v = texcl + local[i];
    cnt[tid * SPAD + i] = v;
    o2[tid * NSEG + i] = estart + v;
  }
  __syncthreads();
  for (int e = estart + tid; e < eend; e += 256) {
    unsigned p = G.pairs[e];
    int key = (int)((p >> 16) * SPAD + ((p & 0xFFFFu) >> 12));
    int lpos = atomicAdd(&cnt[key], 1);
    if (lpos < BSTRIDE)
      stage[lpos] = (unsigned short)(p & 0xFFFFu);
  }
  __syncthreads();
  for (int i = tid; i < count; i += 256)
    G.csr[estart + i] = (int)stage[i];
}

// gather aggregation, graph-major fused. R13: a block's ~29 nodes have
// CONTIGUOUS csr runs (scat2 dst-major sort) -> stage them into LDS with
// per-wave coalesced bursts. Inner loop reads indices from LDS: removes the
// first hop of the 2-hop dependent gather chain (csr->h2) and the 9x
// redundant csr line traffic. Element order preserved -> bitwise-identical.
__global__ __launch_bounds__(256) void k_agg(GT t) {
  const int g = blockIdx.x / AGGB;
  const GP G = t.g[g];
  const int bx = blockIdx.x - g * AGGB;
  const int base_gid = bx * 256;
  const int tid = threadIdx.x;
  const int gid = base_gid + tid;
  const bool active = (gid < NN * NH);

  __shared__ int lcsr[LCAP];          // 11264 B staged csr indices
  __shared__ int lgb[MAXND][5];       // per-node absolute seg-group bounds
  __shared__ int lofs[MAXND + 1];     // per-node start in lcsr

  const int nlo = base_gid / NH;
  int ghi = base_gid + 255;
  if (ghi > NN * NH - 1) ghi = NN * NH - 1;
  const int nhi = ghi / NH;
  const int nn = nhi - nlo + 1;       // <= 30

  if (tid < nn * 5) {
    const int j = tid / 5;
    const int k = tid - j * 5;
    const int col = (k == 4) ? 13 : k * 4;
    lgb[j][k] = G.offs2[(((size_t)(nlo + j)) << 4) + col];
  }
  __syncthreads();
  if (tid == 0) {
    int run = 0;
    for (int j = 0; j < nn; ++j) {
      lofs[j] = run;
      run += lgb[j][4] - lgb[j][0];
    }
    lofs[nn] = run;
  }
  __syncthreads();
  // stage: one node per wave at a time (runs are short, ~33 edges; coalesced)
  {
    const int wv = tid >> 6;
    const int ln = tid & 63;
    for (int j = wv; j < nn; j += 4) {
      const int s0 = lgb[j][0];
      const int len = lgb[j][4] - s0;
      const int base = lofs[j];
      for (int i = ln; i < len; i += 64)
        if (base + i < LCAP) lcsr[base + i] = G.csr[s0 + i];
    }
  }
  __syncthreads();

  int n = 0, head = 0;
  if (active) { n = gid / NH; head = gid - n * NH; }
  float denom = 0.f;
  float4 acc0 = make_float4(0.f, 0.f, 0.f, 0.f);
  float4 acc1 = make_float4(0.f, 0.f, 0.f, 0.f);
  float ad_n = 0.f;
  float4 As0 = make_float4(0.f, 0.f, 0.f, 0.f);
  float4 As1 = make_float4(0.f, 0.f, 0.f, 0.f);
  int gb[5] = {0, 0, 0, 0, 0};
  if (active) {
    ad_n = G.a_d[n * NH + head];
    As0 = *(const float4*)(G.as + head * NC);
    As1 = *(const float4*)(G.as + head * NC + 4);
    const int jj = n - nlo;
    const int rebase = lofs[jj] - lgb[jj][0];   // absolute -> LDS-local
    gb[0] = lgb[jj][0] + rebase; gb[1] = lgb[jj][1] + rebase;
    gb[2] = lgb[jj][2] + rebase; gb[3] = lgb[jj][3] + rebase;
    gb[4] = lgb[jj][4] + rebase;
    const uint4 hs = G.h2[(size_t)n * NH + head];
    accum2(hs, As0, As1, ad_n, denom, acc0, acc1);   // self-loop
  }
  #pragma unroll
  for (int sgrp = 0; sgrp < 4; ++sgrp) {
    int e = gb[sgrp];
    const int en = gb[sgrp + 1];
    for (; e + 4 <= en; e += 4) {
      const int s0 = lcsr[e];
      const int s1 = lcsr[e + 1];
      const int s2 = lcsr[e + 2];
      const int s3 = lcsr[e + 3];
      const uint4 v0 = G.h2[(size_t)s0 * NH + head];
      const uint4 v1 = G.h2[(size_t)s1 * NH + head];
      const uint4 v2 = G.h2[(size_t)s2 * NH + head];
      const uint4 v3 = G.h2[(size_t)s3 * NH + head];
      accum2(v0, As0, As1, ad_n, denom, acc0, acc1);
      accum2(v1, As0, As1, ad_n, denom, acc0, acc1);
      accum2(v2, As0, As1, ad_n, denom, acc0, acc1);
      accum2(v3, As0, As1, ad_n, denom, acc0, acc1);
    }
    for (; e < en; ++e) {
      const int src = lcsr[e];
      const uint4 hv = G.h2[(size_t)src * NH + head];
      accum2(hv, As0, As1, ad_n, denom, acc0, acc1);
    }
    __syncthreads();
  }
  if (!active) return;
  float inv = 1.f / (denom + 1e-16f);
  const float* bp = G.b + head * NC;
  float4 o0, o1;
  o0.x = acc0.x * inv + bp[0]; o0.y = acc0.y * inv + bp[1];
  o0.z = acc0.z * inv + bp[2]; o0.w = acc0.w * inv + bp[3];
  o1.x = acc1.x * inv + bp[4]; o1.y = acc1.y * inv + bp[5];
  o1.z = acc1.z * inv + bp[6]; o1.w = acc1.w * inv + bp[7];
  float4* op = (float4*)(G.out + (size_t)n * HCH + head * NC);
  op[0] = o0; op[1] = o1;
}

// relu(concat) @ fnn_W + fnn_b -> softmax(2). One wave per node.
__global__ __launch_bounds__(256) void k_fnn(const float* __restrict__ o1,
                                             const float* __restrict__ o2,
                                             const float* __restrict__ o3,
                                             const float* __restrict__ fw,
                                             const float* __restrict__ fb,
                                             float* __restrict__ out) {
  const int tid = blockIdx.x * 256 + threadIdx.x;
  const int n = tid >> 6;
  const int lane = tid & 63;
  if (n >= NN) return;
  float acc0 = 0.f, acc1 = 0.f;
  for (int j = lane; j < 3 * HCH; j += 64) {
    const int g = j / HCH;
    const int c = j - g * HCH;
    const float* og = (g == 0) ? o1 : (g == 1) ? o2 : o3;
    float v = og[(size_t)n * HCH + c];
    v = v > 0.f ? v : 0.f;
    acc0 = fmaf(v, fw[2 * j], acc0);
    acc1 = fmaf(v, fw[2 * j + 1], acc1);
  }
  #pragma unroll
  for (int off = 32; off > 0; off >>= 1) {
    acc0 += __shfl_down(acc0, off, 64);
    acc1 += __shfl_down(acc1, off, 64);
  }
  if (lane == 0) {
    float l0 = acc0 + fb[0], l1 = acc1 + fb[1];
    float m = fmaxf(l0, l1);
    float e0 = __expf(l0 - m), e1 = __expf(l1 - m);
    float inv = 1.f / (e0 + e1);
    out[(size_t)n * 2] = e0 * inv;
    out[(size_t)n * 2 + 1] = e1 * inv;
  }
}

extern "C" void kernel_launch(void* const* d_in, const int* in_sizes, int n_in,
                              void* d_out, int out_size, void* d_ws, size_t ws_size,
                              hipStream_t stream) {
  (void)in_sizes; (void)n_in; (void)out_size; (void)ws_size;
  GT t;
  char* w = (char*)d_ws;
  size_t off = 0;
  auto carve = [&](size_t bytes) -> void* {
    void* p = w + off;
    off = (off + bytes + 255) & ~(size_t)255;
    return p;
  };
  int* bc_all = (int*)carve(3 * NBUCK * BCSTRIDE * 4);   // 3 graphs' padded bcursor
  for (int g = 0; g < 3; ++g) {
    GP& G = t.g[g];
    G.x  = (const float*)d_in[6 * g + 0];
    G.ei = (const int*)d_in[6 * g + 1];     // harness stores int64 inputs as int32
    G.W  = (const float*)d_in[6 * g + 2];
    G.as = (const float*)d_in[6 * g + 3];
    G.ad = (const float*)d_in[6 * g + 4];
    G.b  = (const float*)d_in[6 * g + 5];
    G.bcursor = bc_all + g * NBUCK * BCSTRIDE;
    G.h2   = (uint4*)carve((size_t)NN * NH * 16);
    G.a_d  = (float*)carve((size_t)NN * NH * 4);
    G.out  = (float*)carve((size_t)NN * HCH * 4);
    G.wf   = (_Float16*)carve((size_t)4 * 5 * 64 * 8 * 2);
    G.offs2 = (int*)carve((size_t)NBUCK * 256 * NSEG * 4);
    G.pairs = (unsigned int*)carve((size_t)NBUCK * BSTRIDE * 4);
    G.csr   = (int*)carve((size_t)NBUCK * BSTRIDE * 4);
  }
  const float* fw = (const float*)d_in[18];
  const float* fb = (const float*)d_in[19];
  float* outp = (float*)d_out;

  dim3 b256(256, 1, 1);
  k_wpack <<<dim3(1, 1, 3), b256, 0, stream>>>(t);
  k_fat   <<<dim3(BINB + GEMMB2, 1, 3), b256, 0, stream>>>(t);
  k_scat2 <<<dim3(NBUCK, 1, 3), b256, 0, stream>>>(t);
  k_agg   <<<dim3(AGGB * 3, 1, 1), b256, 0, stream>>>(t);
  k_fnn   <<<(NN * 64 + 255) / 256, b256, 0, stream>>>(t.g[0].out, t.g[1].out, t.g[2].out, fw, fb, outp);
}

// Round 14
// 356.315 us; speedup vs baseline: 1.0837x; 1.0243x over previous
//
#include <hip/hip_runtime.h>
#include <hip/hip_fp16.h>

#define NN 50000
#define NE 1600000
#define DD 128
#define NH 9
#define NC 8
#define HCH 72
#define NEG 0.2f
#define NBUCK 196      // ceil(50000/256), 256 dst nodes per bucket
#define NSEG 16        // src segments of 4096 nodes (only 0..12 non-empty)
#define SPAD 17        // padded seg stride in k_scat2 LDS (bank-conflict fix)
#define EPB 16         // edges per thread in bin part
#define BCH (256*EPB)  // 4096 edges per bin block
#define BSTRIDE 10240  // fixed per-bucket capacity (mean 8192, sigma 90 -> +22 sigma)
#define BCSTRIDE 16    // bcursor padded to 64B/bucket
#define GEMMB2 ((NN + 63) / 64)          // 782 mfma-gemm blocks (64 nodes each)
#define BINB ((NE + BCH - 1) / BCH)      // 391 bin blocks
#define AGGB ((NN * NH + 255) / 256)     // 1758 agg blocks per graph
#define CLP 88         // padded col-stride of C LDS tile (fp16)
#define MAXND 30       // max nodes per agg block (ceil(256/9)+1)
#define LCAP 2816      // LDS csr capacity per agg block (mean 928, +62 sigma)

typedef _Float16 f16x8 __attribute__((ext_vector_type(8)));
typedef _Float16 f16x2 __attribute__((ext_vector_type(2)));
typedef float f32x4 __attribute__((ext_vector_type(4)));

__device__ __forceinline__ unsigned short f2h(float f) {
  return __half_as_ushort(__float2half_rn(f));
}
__device__ __forceinline__ float h2f(unsigned short u) {
  return __half2float(__ushort_as_half(u));
}
__device__ __forceinline__ float hlo(unsigned u) {
  return __half2float(__ushort_as_half((unsigned short)(u & 0xFFFFu)));
}
__device__ __forceinline__ float hhi(unsigned u) {
  return __half2float(__ushort_as_half((unsigned short)(u >> 16)));
}
__device__ __forceinline__ f16x2 u2h2(unsigned u) {
  return __builtin_bit_cast(f16x2, u);
}

struct GP {
  const float* x; const int* ei; const float* W;
  const float* as; const float* ad; const float* b;
  uint4* h2;                // [NN*9] uint4: 8 fp16 channels per (node,head)
  float* a_d; float* out;
  _Float16* wf;             // [4*5*64*8] fragment-ordered fp16 W (20KB, k_wpack)
  int* offs2;               // [NBUCK*256*16] per-(node,seg) absolute csr offsets
  int* bcursor;             // [NBUCK*BCSTRIDE] bucket fill counts (64B-padded, atomic)
  unsigned int* pairs;      // [NBUCK*BSTRIDE] strided bucket runs
  int* csr;                 // [NBUCK*BSTRIDE]
};
struct GT { GP g[3]; };

// R14 ALU-thinned edge op: a_s dot = 4 chained v_dot2_f32_f16 on raw fp16
// pairs (ad_n folded as seed); leaky = fmaxf(s, 0.2s) (identical values);
// each h2f result single-use -> backend folds cvt into v_fma_mix_f32.
// ~17 VALU ops/edge vs accum2's ~27.
__device__ __forceinline__ void accum3(uint4 v, f16x2 a01, f16x2 a23,
                                       f16x2 a45, f16x2 a67,
                                       float ad_n, float& denom,
                                       float4& acc0, float4& acc1) {
  const float s = __builtin_amdgcn_fdot2(u2h2(v.w), a67,
                  __builtin_amdgcn_fdot2(u2h2(v.z), a45,
                  __builtin_amdgcn_fdot2(u2h2(v.y), a23,
                  __builtin_amdgcn_fdot2(u2h2(v.x), a01, ad_n, false),
                  false), false), false);
  const float tt = fmaxf(s, NEG * s);   // leaky-relu, branchless, exact
  const float w = __expf(tt);
  denom += w;
  acc0.x = fmaf(w, hlo(v.x), acc0.x); acc0.y = fmaf(w, hhi(v.x), acc0.y);
  acc0.z = fmaf(w, hlo(v.y), acc0.z); acc0.w = fmaf(w, hhi(v.y), acc0.w);
  acc1.x = fmaf(w, hlo(v.z), acc1.x); acc1.y = fmaf(w, hhi(v.z), acc1.y);
  acc1.z = fmaf(w, hlo(v.w), acc1.z); acc1.w = fmaf(w, hhi(v.w), acc1.w);
}

// Pre-pack W into MFMA B-fragment order, fp16, ONCE per graph. Also zeroes
// bcursor (folded from the former hipMemsetAsync dispatch).
__global__ __launch_bounds__(256) void k_wpack(GT t) {
  const GP G = t.g[blockIdx.z];
  const int tid = threadIdx.x;
  for (int i = tid; i < NBUCK * BCSTRIDE; i += 256) G.bcursor[i] = 0;
  for (int idx = tid; idx < 4 * 5 * 64 * 8; idx += 256) {
    const int j = idx & 7;
    const int lane = (idx >> 3) & 63;
    const int ctks = idx >> 9;           // 0..19
    const int ct = ctks % 5;
    const int ks = ctks / 5;
    const int k = ks * 32 + ((lane >> 4) << 3) + j;
    const int col = ct * 16 + (lane & 15);
    const float v = (col < HCH) ? G.W[k * HCH + col] : 0.f;
    G.wf[idx] = (_Float16)v;
  }
}

// Fused bin + gemm (independent stages overlap on the CUs).
__global__ __launch_bounds__(256) void k_fat(GT t) {
  const GP G = t.g[blockIdx.z];
  __shared__ __align__(16) char smem[23072];   // union: bin 23.0KB / gemm 11.3KB
  const int tid = threadIdx.x;

  if (blockIdx.x < BINB) {
    // ---- bin part ----
    unsigned* stage = (unsigned*)smem;                       // 16384 B
    unsigned char* bkt = (unsigned char*)(smem + 16384);     // 4096 B
    int* hist   = (int*)(smem + 20480);                      // 784 B
    int* gdelta = (int*)(smem + 21264);                      // 784 B
    int* ssum   = (int*)(smem + 22048);                      // 1024 B
    const int e0 = blockIdx.x * BCH;

    for (int i = tid; i < NBUCK; i += 256) hist[i] = 0;
    __syncthreads();
    int dsts[EPB], srcs[EPB];
    #pragma unroll
    for (int k = 0; k < EPB; ++k) {
      const int e = e0 + k * 256 + tid;
      if (e < NE) {
        dsts[k] = G.ei[NE + e];
        srcs[k] = G.ei[e];
        atomicAdd(&hist[dsts[k] >> 8], 1);
      } else dsts[k] = -1;
    }
    __syncthreads();
    const int cnt_t = (tid < NBUCK) ? hist[tid] : 0;
    ssum[tid] = cnt_t;
    __syncthreads();
    int run = cnt_t;
    for (int off = 1; off < 256; off <<= 1) {
      int u = (tid >= off) ? ssum[tid - off] : 0;
      __syncthreads();
      run += u;
      ssum[tid] = run;
      __syncthreads();
    }
    const int excl = run - cnt_t;
    if (tid < NBUCK) {
      const int gbase = cnt_t ? atomicAdd(&G.bcursor[tid * BCSTRIDE], cnt_t) : 0;
      gdelta[tid] = tid * BSTRIDE + gbase - excl;
      hist[tid] = excl;                  // counts dead; reuse as scatter cursors
    }
    __syncthreads();
    #pragma unroll
    for (int k = 0; k < EPB; ++k) {
      if (dsts[k] >= 0) {
        const int b = dsts[k] >> 8;
        const int pos = atomicAdd(&hist[b], 1);
        stage[pos] = (unsigned)srcs[k] | ((unsigned)(dsts[k] & 255) << 16);
        bkt[pos] = (unsigned char)b;
      }
    }
    __syncthreads();
    const int total = (e0 + BCH <= NE) ? BCH : (NE - e0);
    for (int i = tid; i < total; i += 256) {
      const int b = bkt[i];
      const int addr = gdelta[b] + i;
      if (addr - b * BSTRIDE < BSTRIDE)
        G.pairs[addr] = stage[i];
    }
    return;
  }

  // ---- gemm part ----
  _Float16* Cl = (_Float16*)smem;                      // [64][CLP] 11264 B
  const int wv = tid >> 6;
  const int ln = tid & 63;
  const int rl = ln & 15;
  const int kg = ln >> 4;
  const int n0 = (blockIdx.x - BINB) << 6;
  int arow = n0 + wv * 16 + rl;
  if (arow >= NN) arow = NN - 1;
  const float4* xr = (const float4*)(G.x + (size_t)arow * DD) + (kg << 1);
  const f16x8* wfp = (const f16x8*)G.wf;

  f32x4 acc[5];
  #pragma unroll
  for (int ct = 0; ct < 5; ++ct) acc[ct] = (f32x4){0.f, 0.f, 0.f, 0.f};

  #pragma unroll
  for (int ks = 0; ks < 4; ++ks) {
    const float4 xa = xr[ks * 8];
    const float4 xb = xr[ks * 8 + 1];
    float xs[8] = {xa.x, xa.y, xa.z, xa.w, xb.x, xb.y, xb.z, xb.w};
    f16x8 ahi, alo;
    #pragma unroll
    for (int j = 0; j < 8; ++j) {
      const _Float16 h = (_Float16)xs[j];
      ahi[j] = h;
      alo[j] = (_Float16)(xs[j] - (float)h);
    }
    #pragma unroll
    for (int ct = 0; ct < 5; ++ct) {
      const f16x8 bf = wfp[(ks * 5 + ct) * 64 + ln];
      acc[ct] = __builtin_amdgcn_mfma_f32_16x16x32_f16(ahi, bf, acc[ct], 0, 0, 0);
      acc[ct] = __builtin_amdgcn_mfma_f32_16x16x32_f16(alo, bf, acc[ct], 0, 0, 0);
    }
  }

  #pragma unroll
  for (int ct = 0; ct < 5; ++ct) {
    #pragma unroll
    for (int j = 0; j < 4; ++j)
      Cl[(wv * 16 + kg * 4 + j) * CLP + ct * 16 + rl] = (_Float16)acc[ct][j];
  }
  __syncthreads();

  for (int p = tid; p < 64 * NH; p += 256) {
    const int node = p / NH;
    const int hd = p - node * NH;
    const int n = n0 + node;
    if (n >= NN) continue;
    const uint4 hv = *(const uint4*)&Cl[node * CLP + hd * NC];
    const float h0 = hlo(hv.x), h1 = hhi(hv.x), h2v = hlo(hv.y), h3 = hhi(hv.y);
    const float h4 = hlo(hv.z), h5 = hhi(hv.z), h6 = hlo(hv.w), h7 = hhi(hv.w);
    const float4 Ad0 = *(const float4*)(G.ad + hd * NC);
    const float4 Ad1 = *(const float4*)(G.ad + hd * NC + 4);
    const float sdst = h0 * Ad0.x + h1 * Ad0.y + h2v * Ad0.z + h3 * Ad0.w
                     + h4 * Ad1.x + h5 * Ad1.y + h6 * Ad1.z + h7 * Ad1.w;
    G.h2[(size_t)n * NH + hd] = hv;
    G.a_d[n * NH + hd] = sdst;
  }
}

// One block per bucket. LDS counting sort with key (dst_local,seg); sorted
// src values staged in LDS ushort, then coalesced copy-out to csr.
__global__ __launch_bounds__(256) void k_scat2(GT t) {
  const GP G = t.g[blockIdx.z];
  const int b = blockIdx.x;
  const int d0 = b << 8;
  __shared__ int cnt[256 * SPAD];
  __shared__ int ssum[256];
  __shared__ unsigned short stage[BSTRIDE];
  const int tid = threadIdx.x;
  const int estart = b * BSTRIDE;
  const int count0 = G.bcursor[b * BCSTRIDE];
  const int count = (count0 < BSTRIDE) ? count0 : BSTRIDE;
  const int eend = estart + count;
  for (int i = tid; i < 256 * SPAD; i += 256) cnt[i] = 0;
  __syncthreads();
  for (int e = estart + tid; e < eend; e += 256) {
    unsigned p = G.pairs[e];
    int key = (int)((p >> 16) * SPAD + ((p & 0xFFFFu) >> 12));
    atomicAdd(&cnt[key], 1);
  }
  __syncthreads();
  int local[NSEG];
  int sum = 0;
  #pragma unroll
  for (int i = 0; i < NSEG; ++i) { local[i] = sum; sum += cnt[tid * SPAD + i]; }
  ssum[tid] = sum;
  __syncthreads();
  int run = sum;
  for (int off = 1; off < 256; off <<= 1) {
    int u = (tid >= off) ? ssum[tid - off] : 0;
    __syncthreads();
    run += u;
    ssum[tid] = run;
    __syncthreads();
  }
  const int texcl = run - sum;
  int* o2 = G.offs2 + ((size_t)d0 << 4);
  #pragma unroll
  for (int i = 0; i < NSEG; ++i) {
    const int v = texcl + local[i];
    cnt[tid * SPAD + i] = v;
    o2[tid * NSEG + i] = estart + v;
  }
  __syncthreads();
  for (int e = estart + tid; e < eend; e += 256) {
    unsigned p = G.pairs[e];
    int key = (int)((p >> 16) * SPAD + ((p & 0xFFFFu) >> 12));
    int lpos = atomicAdd(&cnt[key], 1);
    if (lpos < BSTRIDE)
      stage[lpos] = (unsigned short)(p & 0xFFFFu);
  }
  __syncthreads();
  for (int i = tid; i < count; i += 256)
    G.csr[estart + i] = (int)stage[i];
}

// gather aggregation, ONE GRAPH PER DISPATCH this round (instrumentation:
// agg rows at ~35us let k_fat/k_scat2 surface in the top-5 for the first
// time). R13 LDS csr staging kept; R14 accum3 ALU-thinning applied.
__global__ __launch_bounds__(256) void k_agg(GP G) {
  const int bx = blockIdx.x;
  const int base_gid = bx * 256;
  const int tid = threadIdx.x;
  const int gid = base_gid + tid;
  const bool active = (gid < NN * NH);

  __shared__ int lcsr[LCAP];          // 11264 B staged csr indices
  __shared__ int lgb[MAXND][5];       // per-node absolute seg-group bounds
  __shared__ int lofs[MAXND + 1];     // per-node start in lcsr

  const int nlo = base_gid / NH;
  int ghi = base_gid + 255;
  if (ghi > NN * NH - 1) ghi = NN * NH - 1;
  const int nhi = ghi / NH;
  const int nn = nhi - nlo + 1;       // <= 30

  if (tid < nn * 5) {
    const int j = tid / 5;
    const int k = tid - j * 5;
    const int col = (k == 4) ? 13 : k * 4;
    lgb[j][k] = G.offs2[(((size_t)(nlo + j)) << 4) + col];
  }
  __syncthreads();
  if (tid == 0) {
    int run = 0;
    for (int j = 0; j < nn; ++j) {
      lofs[j] = run;
      run += lgb[j][4] - lgb[j][0];
    }
    lofs[nn] = run;
  }
  __syncthreads();
  // stage: one node per wave at a time (runs are short, ~33 edges; coalesced)
  {
    const int wv = tid >> 6;
    const int ln = tid & 63;
    for (int j = wv; j < nn; j += 4) {
      const int s0 = lgb[j][0];
      const int len = lgb[j][4] - s0;
      const int base = lofs[j];
      for (int i = ln; i < len; i += 64)
        if (base + i < LCAP) lcsr[base + i] = G.csr[s0 + i];
    }
  }
  __syncthreads();

  int n = 0, head = 0;
  if (active) { n = gid / NH; head = gid - n * NH; }
  float denom = 0.f;
  float4 acc0 = make_float4(0.f, 0.f, 0.f, 0.f);
  float4 acc1 = make_float4(0.f, 0.f, 0.f, 0.f);
  float ad_n = 0.f;
  f16x2 a01 = (f16x2){(_Float16)0.f, (_Float16)0.f};
  f16x2 a23 = a01, a45 = a01, a67 = a01;
  int gb[5] = {0, 0, 0, 0, 0};
  if (active) {
    ad_n = G.a_d[n * NH + head];
    const float4 As0 = *(const float4*)(G.as + head * NC);
    const float4 As1 = *(const float4*)(G.as + head * NC + 4);
    a01 = (f16x2){(_Float16)As0.x, (_Float16)As0.y};
    a23 = (f16x2){(_Float16)As0.z, (_Float16)As0.w};
    a45 = (f16x2){(_Float16)As1.x, (_Float16)As1.y};
    a67 = (f16x2){(_Float16)As1.z, (_Float16)As1.w};
    const int jj = n - nlo;
    const int rebase = lofs[jj] - lgb[jj][0];   // absolute -> LDS-local
    gb[0] = lgb[jj][0] + rebase; gb[1] = lgb[jj][1] + rebase;
    gb[2] = lgb[jj][2] + rebase; gb[3] = lgb[jj][3] + rebase;
    gb[4] = lgb[jj][4] + rebase;
    const uint4 hs = G.h2[(size_t)n * NH + head];
    accum3(hs, a01, a23, a45, a67, ad_n, denom, acc0, acc1);   // self-loop
  }
  #pragma unroll
  for (int sgrp = 0; sgrp < 4; ++sgrp) {
    int e = gb[sgrp];
    const int en = gb[sgrp + 1];
    for (; e + 4 <= en; e += 4) {
      const int s0 = lcsr[e];
      const int s1 = lcsr[e + 1];
      const int s2 = lcsr[e + 2];
      const int s3 = lcsr[e + 3];
      const uint4 v0 = G.h2[(size_t)s0 * NH + head];
      const uint4 v1 = G.h2[(size_t)s1 * NH + head];
      const uint4 v2 = G.h2[(size_t)s2 * NH + head];
      const uint4 v3 = G.h2[(size_t)s3 * NH + head];
      accum3(v0, a01, a23, a45, a67, ad_n, denom, acc0, acc1);
      accum3(v1, a01, a23, a45, a67, ad_n, denom, acc0, acc1);
      accum3(v2, a01, a23, a45, a67, ad_n, denom, acc0, acc1);
      accum3(v3, a01, a23, a45, a67, ad_n, denom, acc0, acc1);
    }
    for (; e < en; ++e) {
      const int src = lcsr[e];
      const uint4 hv = G.h2[(size_t)src * NH + head];
      accum3(hv, a01, a23, a45, a67, ad_n, denom, acc0, acc1);
    }
    __syncthreads();
  }
  if (!active) return;
  float inv = 1.f / (denom + 1e-16f);
  const float* bp = G.b + head * NC;
  float4 o0, o1;
  o0.x = acc0.x * inv + bp[0]; o0.y = acc0.y * inv + bp[1];
  o0.z = acc0.z * inv + bp[2]; o0.w = acc0.w * inv + bp[3];
  o1.x = acc1.x * inv + bp[4]; o1.y = acc1.y * inv + bp[5];
  o1.z = acc1.z * inv + bp[6]; o1.w = acc1.w * inv + bp[7];
  float4* op = (float4*)(G.out + (size_t)n * HCH + head * NC);
  op[0] = o0; op[1] = o1;
}

// relu(concat) @ fnn_W + fnn_b -> softmax(2). One wave per node.
__global__ __launch_bounds__(256) void k_fnn(const float* __restrict__ o1,
                                             const float* __restrict__ o2,
                                             const float* __restrict__ o3,
                                             const float* __restrict__ fw,
                                             const float* __restrict__ fb,
                                             float* __restrict__ out) {
  const int tid = blockIdx.x * 256 + threadIdx.x;
  const int n = tid >> 6;
  const int lane = tid & 63;
  if (n >= NN) return;
  float acc0 = 0.f, acc1 = 0.f;
  for (int j = lane; j < 3 * HCH; j += 64) {
    const int g = j / HCH;
    const int c = j - g * HCH;
    const float* og = (g == 0) ? o1 : (g == 1) ? o2 : o3;
    float v = og[(size_t)n * HCH + c];
    v = v > 0.f ? v : 0.f;
    acc0 = fmaf(v, fw[2 * j], acc0);
    acc1 = fmaf(v, fw[2 * j + 1], acc1);
  }
  #pragma unroll
  for (int off = 32; off > 0; off >>= 1) {
    acc0 += __shfl_down(acc0, off, 64);
    acc1 += __shfl_down(acc1, off, 64);
  }
  if (lane == 0) {
    float l0 = acc0 + fb[0], l1 = acc1 + fb[1];
    float m = fmaxf(l0, l1);
    float e0 = __expf(l0 - m), e1 = __expf(l1 - m);
    float inv = 1.f / (e0 + e1);
    out[(size_t)n * 2] = e0 * inv;
    out[(size_t)n * 2 + 1] = e1 * inv;
  }
}

extern "C" void kernel_launch(void* const* d_in, const int* in_sizes, int n_in,
                              void* d_out, int out_size, void* d_ws, size_t ws_size,
                              hipStream_t stream) {
  (void)in_sizes; (void)n_in; (void)out_size; (void)ws_size;
  GT t;
  char* w = (char*)d_ws;
  size_t off = 0;
  auto carve = [&](size_t bytes) -> void* {
    void* p = w + off;
    off = (off + bytes + 255) & ~(size_t)255;
    return p;
  };
  int* bc_all = (int*)carve(3 * NBUCK * BCSTRIDE * 4);   // 3 graphs' padded bcursor
  for (int g = 0; g < 3; ++g) {
    GP& G = t.g[g];
    G.x  = (const float*)d_in[6 * g + 0];
    G.ei = (const int*)d_in[6 * g + 1];     // harness stores int64 inputs as int32
    G.W  = (const float*)d_in[6 * g + 2];
    G.as = (const float*)d_in[6 * g + 3];
    G.ad = (const float*)d_in[6 * g + 4];
    G.b  = (const float*)d_in[6 * g + 5];
    G.bcursor = bc_all + g * NBUCK * BCSTRIDE;
    G.h2   = (uint4*)carve((size_t)NN * NH * 16);
    G.a_d  = (float*)carve((size_t)NN * NH * 4);
    G.out  = (float*)carve((size_t)NN * HCH * 4);
    G.wf   = (_Float16*)carve((size_t)4 * 5 * 64 * 8 * 2);
    G.offs2 = (int*)carve((size_t)NBUCK * 256 * NSEG * 4);
    G.pairs = (unsigned int*)carve((size_t)NBUCK * BSTRIDE * 4);
    G.csr   = (int*)carve((size_t)NBUCK * BSTRIDE * 4);
  }
  const float* fw = (const float*)d_in[18];
  const float* fb = (const float*)d_in[19];
  float* outp = (float*)d_out;

  dim3 b256(256, 1, 1);
  k_wpack <<<dim3(1, 1, 3), b256, 0, stream>>>(t);
  k_fat   <<<dim3(BINB + GEMMB2, 1, 3), b256, 0, stream>>>(t);
  k_scat2 <<<dim3(NBUCK, 1, 3), b256, 0, stream>>>(t);
  for (int g = 0; g < 3; ++g)
    k_agg <<<dim3(AGGB, 1, 1), b256, 0, stream>>>(t.g[g]);
  k_fnn   <<<(NN * 64 + 255) / 256, b256, 0, stream>>>(t.g[0].out, t.g[1].out, t.g[2].out, fw, fb, outp);
}